// Round 4
// baseline (423.148 us; speedup 1.0000x reference)
//
#include <hip/hip_runtime.h>

typedef __bf16 bf16;
typedef __attribute__((ext_vector_type(8))) __bf16 bf16x8;
typedef __attribute__((ext_vector_type(4))) float f32x4;

#define MFMA16(a, b, c) __builtin_amdgcn_mfma_f32_16x16x32_bf16(a, b, c, 0, 0, 0)

__device__ __forceinline__ int div7(int n) { return (n * 37) >> 8; }          // exact 0..63
__device__ __forceinline__ int relv(int n) { int r = div7(n); return 13 * r + (n - 7 * r); }

// Load 8 consecutive fp32 elements, round to bf16x8 (RNE via cast).
__device__ __forceinline__ bf16x8 LD8(const float* p) {
    f32x4 a = *(const f32x4*)p;
    f32x4 b = *(const f32x4*)(p + 4);
    bf16x8 r;
    r[0] = (bf16)a[0]; r[1] = (bf16)a[1]; r[2] = (bf16)a[2]; r[3] = (bf16)a[3];
    r[4] = (bf16)b[0]; r[5] = (bf16)b[1]; r[6] = (bf16)b[2]; r[7] = (bf16)b[3];
    return r;
}

// One block = one 7x7 window. 256 threads = 4 waves.
__global__ __launch_bounds__(256, 2)
void swin_msa_kernel(const float* __restrict__ x_in,   const float* __restrict__ sx_in,
                     const float* __restrict__ qkv_w,  const float* __restrict__ qkv_b,
                     const float* __restrict__ skip_w, const float* __restrict__ skip_b,
                     const float* __restrict__ proj_w, const float* __restrict__ proj_b,
                     const float* __restrict__ btab,   float* __restrict__ out)
{
    // LDS: X(64x104) SX(64x104) K(64x96) Q(64x96) VT(96x72)  = 65024 B (+256 B G)
    __shared__ __align__(16) unsigned short smem[32512];
    __shared__ int G[64];

    bf16* X  = (bf16*)smem;   // 64 x 104
    bf16* SX = X  + 6656;     // 64 x 104
    bf16* Kb = SX + 6656;     // 64 x 96
    bf16* Qb = Kb + 6144;     // 64 x 96
    bf16* VT = Qb + 6144;     // 96 x 72  (V transposed: [channel][pixel])
    bf16* P  = SX;            // alias: 4 x (16 x 72) per-wave prob tiles (SX dead after barrier 2)
    bf16* Ob = X;             // alias: 64 x 104 attention output (X dead after barrier 2)

    const int tid  = threadIdx.x;
    const int wv   = tid >> 6;
    const int lane = tid & 63;
    const int quad = lane >> 4;
    const int l16  = lane & 15;

    const int win  = blockIdx.x;
    const int bimg = win >> 10;
    const int wrem = win & 1023;
    const int wi   = wrem >> 5;
    const int wj   = wrem & 31;

    const f32x4 zero4 = {0.f, 0.f, 0.f, 0.f};
    const bf16x8 zero8 = {(bf16)0.f,(bf16)0.f,(bf16)0.f,(bf16)0.f,(bf16)0.f,(bf16)0.f,(bf16)0.f,(bf16)0.f};

    // ---- stage -1: zero all of smem (pads are correct zeros; no uninit reads) -
    {
        bf16x8* z = (bf16x8*)smem;            // 4064 vectors of 8 bf16
        for (int i = tid; i < 4064; i += 256) z[i] = zero8;
    }
    __syncthreads();

    // ---- stage 0: region ids for the shift mask (rolled coords) ---------------
    if (tid < 64) {
        int g = 0;
        if (tid < 49) {
            int r = div7(tid), c = tid - 7 * r;
            int hr = wi * 7 + r, wc = wj * 7 + c;
            int fh = (hr < 217) ? 0 : ((hr < 221) ? 1 : 2);
            int fw = (wc < 217) ? 0 : ((wc < 221) ? 1 : 2);
            g = fh * 3 + fw;
        }
        G[tid] = g;
    }

    // ---- stage 1: gather window (roll -3) into LDS (rows < 49) ----------------
    // 2 arrays x 49 rows x 12 segs of 8 elements = 1176 tasks
    for (int it = 0; it < 5; ++it) {
        int t = tid + it * 256;
        if (t < 1176) {
            int arr = t / 588;
            int rem = t - arr * 588;
            int row = (rem * 683) >> 13;      // rem / 12, exact for rem < 768
            int seg = rem - row * 12;
            int r  = div7(row), c = row - 7 * r;
            int h0 = wi * 7 + r + 3; if (h0 >= 224) h0 -= 224;   // roll(-3) gather
            int w0 = wj * 7 + c + 3; if (w0 >= 224) w0 -= 224;
            int off = ((bimg * 224 + h0) * 224 + w0) * 96 + seg * 8;
            bf16x8 v = LD8((arr ? sx_in : x_in) + off);
            *(bf16x8*)((arr ? SX : X) + row * 104 + seg * 8) = v;
        }
    }
    __syncthreads();

    // ---- stage 2a: KV = X @ qkv_w^T + qkv_b  (M=64, N=192 split across waves) -
    {
        f32x4 acc[4][3];
        #pragma unroll
        for (int m = 0; m < 4; ++m)
            #pragma unroll
            for (int t = 0; t < 3; ++t) acc[m][t] = zero4;

        #pragma unroll
        for (int ks = 0; ks < 3; ++ks) {
            const int k0 = ks * 32 + quad * 8;
            bf16x8 a[4];
            #pragma unroll
            for (int m = 0; m < 4; ++m)
                a[m] = *(const bf16x8*)(X + (16 * m + l16) * 104 + k0);
            #pragma unroll
            for (int t = 0; t < 3; ++t) {
                const int ncol = (3 * wv + t) * 16 + l16;
                bf16x8 b = LD8(qkv_w + ncol * 96 + k0);
                #pragma unroll
                for (int m = 0; m < 4; ++m) acc[m][t] = MFMA16(a[m], b, acc[m][t]);
            }
        }
        #pragma unroll
        for (int t = 0; t < 3; ++t) {
            const int ncol = (3 * wv + t) * 16 + l16;
            const float bias = qkv_b[ncol];
            #pragma unroll
            for (int m = 0; m < 4; ++m)
                #pragma unroll
                for (int r = 0; r < 4; ++r) {
                    int row = 16 * m + quad * 4 + r;
                    float val = acc[m][t][r] + bias;
                    if (ncol < 96) Kb[row * 96 + ncol] = (bf16)val;
                    else           VT[(ncol - 96) * 72 + row] = (bf16)val;
                }
        }
    }

    // ---- stage 2b: Q = SX @ skip_w^T + skip_b  (wave owns 16 query rows) ------
    {
        f32x4 acc[6];
        #pragma unroll
        for (int t = 0; t < 6; ++t) acc[t] = zero4;
        #pragma unroll
        for (int ks = 0; ks < 3; ++ks) {
            const int k0 = ks * 32 + quad * 8;
            bf16x8 a = *(const bf16x8*)(SX + (16 * wv + l16) * 104 + k0);
            #pragma unroll
            for (int t = 0; t < 6; ++t) {
                bf16x8 b = LD8(skip_w + (16 * t + l16) * 96 + k0);
                acc[t] = MFMA16(a, b, acc[t]);
            }
        }
        #pragma unroll
        for (int t = 0; t < 6; ++t) {
            const int col = 16 * t + l16;
            const float bias = skip_b[col];
            #pragma unroll
            for (int r = 0; r < 4; ++r) {
                int row = 16 * wv + quad * 4 + r;
                Qb[row * 96 + col] = (bf16)(acc[t][r] + bias);
            }
        }
    }
    __syncthreads();   // K, V^T, Q visible; X/SX dead from here on

    // ---- stage 3: attention (wave-private) ------------------------------------
    int  rvm[4], gm[4];  bool mok[4];
    #pragma unroll
    for (int nt = 0; nt < 4; ++nt) {
        int m  = nt * 16 + l16;
        mok[nt] = (m < 49);
        int mm = mok[nt] ? m : 48;
        rvm[nt] = relv(48 - mm);          // flipped key index
        gm[nt]  = G[mm];
    }
    int rvn[4], gn[4];
    #pragma unroll
    for (int r = 0; r < 4; ++r) {
        int n  = 16 * wv + quad * 4 + r;
        int nc = (n < 49) ? n : 48;
        rvn[r] = relv(nc);
        gn[r]  = G[nc];
    }

    const float scale = 0.17677669529663687f;   // 32^-0.5
    bf16* Pw = P + wv * (16 * 72);

    for (int h = 0; h < 3; ++h) {
        bf16x8 aq = *(const bf16x8*)(Qb + (16 * wv + l16) * 96 + h * 32 + quad * 8);
        f32x4 s[4];
        #pragma unroll
        for (int nt = 0; nt < 4; ++nt) {
            bf16x8 bk = *(const bf16x8*)(Kb + (nt * 16 + l16) * 96 + h * 32 + quad * 8);
            s[nt] = MFMA16(aq, bk, zero4);
        }
        float val[4][4];
        #pragma unroll
        for (int nt = 0; nt < 4; ++nt)
            #pragma unroll
            for (int r = 0; r < 4; ++r) {
                float x = s[nt][r] * scale + btab[(rvn[r] + rvm[nt]) * 3 + h];
                if (gn[r] != gm[nt]) x -= 100.f;
                val[nt][r] = mok[nt] ? x : -20000.f;
            }
        #pragma unroll
        for (int r = 0; r < 4; ++r) {
            float mx = fmaxf(fmaxf(val[0][r], val[1][r]), fmaxf(val[2][r], val[3][r]));
            mx = fmaxf(mx, __shfl_xor(mx, 1));
            mx = fmaxf(mx, __shfl_xor(mx, 2));
            mx = fmaxf(mx, __shfl_xor(mx, 4));
            mx = fmaxf(mx, __shfl_xor(mx, 8));
            float e0 = __expf(val[0][r] - mx), e1 = __expf(val[1][r] - mx);
            float e2 = __expf(val[2][r] - mx), e3 = __expf(val[3][r] - mx);
            float sm = e0 + e1 + e2 + e3;
            sm += __shfl_xor(sm, 1);
            sm += __shfl_xor(sm, 2);
            sm += __shfl_xor(sm, 4);
            sm += __shfl_xor(sm, 8);
            float inv = 1.0f / sm;
            int prow = (quad * 4 + r) * 72;
            Pw[prow +  0 + l16] = (bf16)(e0 * inv);
            Pw[prow + 16 + l16] = (bf16)(e1 * inv);
            Pw[prow + 32 + l16] = (bf16)(e2 * inv);
            Pw[prow + 48 + l16] = (bf16)(e3 * inv);
        }
        asm volatile("" ::: "memory");
        // O_h = P @ V_h : K=64 (2 steps), d-tiles {0,1}
        f32x4 o0 = zero4, o1 = zero4;
        #pragma unroll
        for (int ks = 0; ks < 2; ++ks) {
            bf16x8 ap = *(const bf16x8*)(Pw + l16 * 72 + ks * 32 + quad * 8);
            bf16x8 b0 = *(const bf16x8*)(VT + (h * 32 +      l16) * 72 + ks * 32 + quad * 8);
            bf16x8 b1 = *(const bf16x8*)(VT + (h * 32 + 16 + l16) * 72 + ks * 32 + quad * 8);
            o0 = MFMA16(ap, b0, o0);
            o1 = MFMA16(ap, b1, o1);
        }
        #pragma unroll
        for (int r = 0; r < 4; ++r) {
            int row = 16 * wv + quad * 4 + r;
            Ob[row * 104 + h * 32 +      l16] = (bf16)o0[r];
            Ob[row * 104 + h * 32 + 16 + l16] = (bf16)o1[r];
        }
        asm volatile("" ::: "memory");
    }

    // ---- stage 4: out = O @ proj_w^T + proj_b, scatter with roll(+3) ----------
    {
        f32x4 acc[6];
        #pragma unroll
        for (int t = 0; t < 6; ++t) acc[t] = zero4;
        #pragma unroll
        for (int ks = 0; ks < 3; ++ks) {
            const int k0 = ks * 32 + quad * 8;
            bf16x8 a = *(const bf16x8*)(Ob + (16 * wv + l16) * 104 + k0);
            #pragma unroll
            for (int t = 0; t < 6; ++t) {
                bf16x8 b = LD8(proj_w + (16 * t + l16) * 96 + k0);
                acc[t] = MFMA16(a, b, acc[t]);
            }
        }
        int  pixoff[4];
        bool rowok[4];
        #pragma unroll
        for (int r = 0; r < 4; ++r) {
            int n = 16 * wv + quad * 4 + r;
            rowok[r] = (n < 49);
            int nc = rowok[r] ? n : 48;
            int rr = div7(nc), cc = nc - 7 * rr;
            int h0 = wi * 7 + rr + 3; if (h0 >= 224) h0 -= 224;  // reverse roll == same pixel
            int w0 = wj * 7 + cc + 3; if (w0 >= 224) w0 -= 224;
            pixoff[r] = ((bimg * 224 + h0) * 224 + w0) * 96;
        }
        #pragma unroll
        for (int t = 0; t < 6; ++t) {
            const int col = 16 * t + l16;
            const float pb = proj_b[col];
            #pragma unroll
            for (int r = 0; r < 4; ++r)
                if (rowok[r]) out[pixoff[r] + col] = acc[t][r] + pb;
        }
    }
}

extern "C" void kernel_launch(void* const* d_in, const int* in_sizes, int n_in,
                              void* d_out, int out_size, void* d_ws, size_t ws_size,
                              hipStream_t stream) {
    (void)in_sizes; (void)n_in; (void)out_size; (void)d_ws; (void)ws_size;
    swin_msa_kernel<<<dim3(4096), dim3(256), 0, stream>>>(
        (const float*)d_in[0], (const float*)d_in[1], (const float*)d_in[2],
        (const float*)d_in[3], (const float*)d_in[4], (const float*)d_in[5],
        (const float*)d_in[6], (const float*)d_in[7], (const float*)d_in[8],
        (float*)d_out);
}